// Round 9
// baseline (224.599 us; speedup 1.0000x reference)
//
#include <hip/hip_runtime.h>
#include <hip/hip_bf16.h>

// Problem dims
#define BD 4096   // batch
#define ID 1024   // input dim
#define HD 1024   // hidden dim
#define KD 2048   // I + H  (concatenated GEMM K)
#define ND 4096   // 4*H    (gate-interleaved GEMM N: col n = r*4 + g)

typedef __attribute__((ext_vector_type(8))) __bf16 bf16x8;
typedef __attribute__((ext_vector_type(16))) float f32x16;

static __device__ __forceinline__ unsigned short f2bf(float f) {
  union { float f; unsigned u; } v; v.f = f;
  unsigned u = v.u;
  unsigned r = u + 0x7fffu + ((u >> 16) & 1u);   // round-to-nearest-even
  return (unsigned short)(r >> 16);
}
static __device__ __forceinline__ float bf2f(unsigned short s) {
  union { unsigned u; float f; } v; v.u = ((unsigned)s) << 16;
  return v.f;
}

static __device__ __forceinline__ void gload_lds16(const void* g, void* l) {
  __builtin_amdgcn_global_load_lds(
      (const __attribute__((address_space(1))) void*)g,
      (__attribute__((address_space(3))) void*)l, 16, 0, 0);
}

// approx-rcp gate math: v_exp_f32 + v_rcp_f32, ~1e-7 rel err, correct saturation.
static __device__ __forceinline__ float fast_sigmoid(float x) {
  return __builtin_amdgcn_rcpf(1.0f + __expf(-x));
}
static __device__ __forceinline__ float fast_tanh(float x) {
  return 2.0f * __builtin_amdgcn_rcpf(1.0f + __expf(-2.0f * x)) - 1.0f;
}

// ---------------- fused pack kernel: f32 -> bf16, A=[x|h], Bm=[Wx|Wh] ----------
// Bm row n corresponds to gate g = n&3 of hidden unit r = n>>2 (gate-interleaved).
__global__ void pack_AB(const float* __restrict__ x, const float* __restrict__ h,
                        const float* __restrict__ wxi, const float* __restrict__ wxf,
                        const float* __restrict__ wxg, const float* __restrict__ wxo,
                        const float* __restrict__ whi, const float* __restrict__ whf,
                        const float* __restrict__ whg, const float* __restrict__ who,
                        unsigned short* __restrict__ A, unsigned short* __restrict__ Bm) {
  if (blockIdx.x < 8192) {
    int idx = blockIdx.x * blockDim.x + threadIdx.x;
    int e = idx << 2;
    int b = e >> 11;
    int k = e & 2047;
    const float* src = (k < ID) ? (x + (size_t)b * ID + k)
                                : (h + (size_t)b * HD + (k - ID));
    float4 v = *reinterpret_cast<const float4*>(src);
    ushort4 o;
    o.x = f2bf(v.x); o.y = f2bf(v.y); o.z = f2bf(v.z); o.w = f2bf(v.w);
    *reinterpret_cast<ushort4*>(A + e) = o;
  } else {
    int idx = (blockIdx.x - 8192) * blockDim.x + threadIdx.x;
    int e = idx << 2;
    int n = e >> 11;
    int k = e & 2047;
    int g = n & 3, r = n >> 2;         // gate-interleaved
    const float* src;
    if (k < ID) {
      src = (g == 0) ? wxi : (g == 1) ? wxf : (g == 2) ? wxg : wxo;
      src += (size_t)r * ID + k;
    } else {
      src = (g == 0) ? whi : (g == 1) ? whf : (g == 2) ? whg : who;
      src += (size_t)r * HD + (k - ID);
    }
    float4 v = *reinterpret_cast<const float4*>(src);
    ushort4 o;
    o.x = f2bf(v.x); o.y = f2bf(v.y); o.z = f2bf(v.z); o.w = f2bf(v.w);
    *reinterpret_cast<ushort4*>(Bm + e) = o;
  }
}

// ---------------- fused GEMM + peephole-LSTM epilogue --------------------------
// z[M][N] = A[M][K] * Bm[N][K]^T with mfma_f32_32x32x16_bf16 (2495 TF pipe rate
// vs 2075 for 16x16), then gates from 4 adjacent cols -> h,c in-block.
// 256x256 tile, BK=64, 8 waves (2Mx4N), double-buffered swizzled LDS, one
// vmcnt(0)+barrier per K-tile (loads aged a full tile body), flat tile body
// (compiler pipelines ds_read under MFMA), setprio, XCD swizzle.
__global__ __launch_bounds__(512, 2) void gemm_lstm(
    const unsigned short* __restrict__ A,   // [4096][2048]
    const unsigned short* __restrict__ Bm,  // [4096][2048]
    const float* __restrict__ c,            // [4096][1024]
    const float* __restrict__ bxi, const float* __restrict__ bhi,
    const float* __restrict__ bxf, const float* __restrict__ bhf,
    const float* __restrict__ bxg, const float* __restrict__ bhg,
    const float* __restrict__ bxo, const float* __restrict__ bho,
    const float* __restrict__ pci, const float* __restrict__ pcf,
    const float* __restrict__ pco,
    float* __restrict__ out) {              // h [4096][1024] | c [4096][1024]
  // K-loop: lds[0..65536) ushorts (A: [2][256][64] at 0, B at 32768).
  // Epilogue reuses as zl[256][264] bf16 (135168 B total).
  __shared__ __attribute__((aligned(16))) unsigned short lds[67584];

  const int tid  = threadIdx.x;     // 0..511
  const int lane = tid & 63;
  const int w    = tid >> 6;        // wave 0..7
  const int wr   = w >> 2;          // 0..1  (wave row: 128 rows)
  const int wc   = w & 3;           // 0..3  (wave col: 64 cols)

  // XCD-aware swizzle: 256 blocks, 8 XCDs, 32 contiguous per XCD (bijective).
  const int bid = blockIdx.x;
  const int swz = (bid & 7) * 32 + (bid >> 3);
  const int m0  = (swz >> 4) * 256;
  const int n0  = (swz & 15) * 256;

  f32x16 acc[4][2];
#pragma unroll
  for (int i = 0; i < 4; ++i)
#pragma unroll
    for (int j = 0; j < 2; ++j)
      acc[i][j] = (f32x16){0.f,0.f,0.f,0.f,0.f,0.f,0.f,0.f,
                           0.f,0.f,0.f,0.f,0.f,0.f,0.f,0.f};

  // per-lane swizzled read offsets; slot = chunk ^ (row&7), row&7 == lane&7
  const int sw  = lane & 7;
  const int hi  = lane >> 5;                     // k-group within fragment
  const int rA0 = (wr * 128 + (lane & 31)) * 64; // A row base (elements)
  const int rB0 = (wc * 64  + (lane & 31)) * 64; // B row base
  int offk[4];
#pragma unroll
  for (int kx = 0; kx < 4; ++kx)
    offk[kx] = ((2 * kx + hi) ^ sw) * 8;         // chunk (2k+hi), swizzled

  unsigned short* ldsA = lds;           // [2][256][64]
  unsigned short* ldsB = lds + 32768;   // [2][256][64]

  // QB: all 256 B rows (4 x gload_lds16 per thread)
  auto stageB = [&](int buf, int kt) {
#pragma unroll
    for (int q = 0; q < 4; ++q) {
      int ci  = q * 512 + tid;          // 16B chunk index 0..2047
      int row = ci >> 3;
      int sc  = (ci & 7) ^ (row & 7);   // inverse-swizzled source chunk
      gload_lds16(Bm + (size_t)(n0 + row) * KD + kt + sc * 8,
                  ldsB + buf * 16384 + (q * 512 + w * 64) * 8);
    }
  };
  // QA_p: A rows {p*32..p*32+31} u {128+p*32..} (1 x gload_lds16 per thread)
  auto stageA = [&](int buf, int kt, int p) {
    int half = tid >> 8;                // wave-uniform (w>>2)
    int idx  = tid & 255;
    int row  = half * 128 + p * 32 + (idx >> 3);
    int sc   = (idx & 7) ^ ((idx >> 3) & 7);
    gload_lds16(A + (size_t)(m0 + row) * KD + kt + sc * 8,
                ldsA + buf * 16384 + (half * 1024 + p * 256 + (w & 3) * 64) * 8);
  };

  // prologue: full tile 0
  stageB(0, 0);
  stageA(0, 0, 0);
  stageA(0, 0, 1);
  stageA(0, 0, 2);
  stageA(0, 0, 3);

  for (int T = 0; T < 32; ++T) {
    const int buf = T & 1;
    const unsigned short* pA = ldsA + buf * 16384;
    const unsigned short* pB = ldsB + buf * 16384;
    const int ktn = (T + 1) * 64;

    // boundary: tile T's loads were issued during T-1 (aged a full body) ->
    // vmcnt(0) is an aged wait, not a drain-of-fresh-issues.
    asm volatile("s_waitcnt vmcnt(0)" ::: "memory");
    __builtin_amdgcn_s_barrier();

    // issue next tile's stages first so they age the longest
    if (T < 31) {
      stageB(buf ^ 1, ktn);
      stageA(buf ^ 1, ktn, 0);
      stageA(buf ^ 1, ktn, 1);
      stageA(buf ^ 1, ktn, 2);
      stageA(buf ^ 1, ktn, 3);
    }
    __builtin_amdgcn_sched_barrier(0);

    // flat tile body: 8 B-frag + 16 A-frag ds_read_b128, 32 MFMA 32x32x16
    bf16x8 bfr[2][4];
#pragma unroll
    for (int ni = 0; ni < 2; ++ni)
#pragma unroll
      for (int kx = 0; kx < 4; ++kx)
        bfr[ni][kx] = *(const bf16x8*)(pB + rB0 + ni * 2048 + offk[kx]);
#pragma unroll
    for (int mi = 0; mi < 4; ++mi) {
      bf16x8 af[4];
#pragma unroll
      for (int kx = 0; kx < 4; ++kx)
        af[kx] = *(const bf16x8*)(pA + rA0 + mi * 2048 + offk[kx]);
      __builtin_amdgcn_s_setprio(1);
#pragma unroll
      for (int ni = 0; ni < 2; ++ni)
#pragma unroll
        for (int kx = 0; kx < 4; ++kx)
          acc[mi][ni] = __builtin_amdgcn_mfma_f32_32x32x16_bf16(
              af[kx], bfr[ni][kx], acc[mi][ni], 0, 0, 0);
      __builtin_amdgcn_s_setprio(0);
    }
  }

  // ---------------- fused epilogue ----------------
  // 1) dump z (bf16) into zl[256][264].
  // 32x32 C/D layout: col = lane&31, row = (reg&3) + 8*(reg>>2) + 4*(lane>>5)
  unsigned short* zl = lds;
  __builtin_amdgcn_s_barrier();   // all K-loop LDS reads complete
#pragma unroll
  for (int mi = 0; mi < 4; ++mi)
#pragma unroll
    for (int ni = 0; ni < 2; ++ni) {
      const int cl = wc * 64 + ni * 32 + (lane & 31);
#pragma unroll
      for (int rg = 0; rg < 16; ++rg) {
        const int rl = wr * 128 + mi * 32 + (rg & 3) + 8 * (rg >> 2) + 4 * hi;
        zl[rl * 264 + cl] = f2bf(acc[mi][ni][rg]);
      }
    }
  __builtin_amdgcn_s_barrier();

  // 2) per-thread: fixed r (=tid&63), rows stride 8; all accesses coalesced.
  {
    const int r_loc = tid & 63;
    const int rg    = (n0 >> 2) + r_loc;      // global hidden-unit index
    const float bi_ = bxi[rg] + bhi[rg];
    const float bf_ = bxf[rg] + bhf[rg];
    const float bg_ = bxg[rg] + bhg[rg];
    const float bo_ = bxo[rg] + bho[rg];
    const float pi_ = pci[rg];
    const float pf_ = pcf[rg];
    const float po_ = pco[rg];
#pragma unroll 4
    for (int it = 0; it < 32; ++it) {
      const int rl  = (tid >> 6) + it * 8;    // wave-uniform row
      const int row = m0 + rl;
      ushort4 zv = *(const ushort4*)&zl[rl * 264 + r_loc * 4];
      float cc = c[(size_t)row * HD + rg];
      float vi = bf2f(zv.x) + bi_ + pi_ * cc;
      float vf = bf2f(zv.y) + bf_ + pf_ * cc;
      float vg = bf2f(zv.z) + bg_;
      float vo = bf2f(zv.w) + bo_;
      float ig = fast_sigmoid(vi);
      float fg = fast_sigmoid(vf);
      float gg = fast_tanh(vg);
      float cnext = fg * cc + ig * gg;
      float og = fast_sigmoid(vo + po_ * cnext);
      out[(size_t)row * HD + rg] = og * fast_tanh(cnext);
      out[(size_t)BD * HD + (size_t)row * HD + rg] = cnext;
    }
  }
}

// ---------------- launch -------------------------------------------------------
extern "C" void kernel_launch(void* const* d_in, const int* in_sizes, int n_in,
                              void* d_out, int out_size, void* d_ws, size_t ws_size,
                              hipStream_t stream) {
  const float* x      = (const float*)d_in[0];
  const float* h      = (const float*)d_in[1];
  const float* c      = (const float*)d_in[2];
  const float* W_ii_w = (const float*)d_in[3];
  const float* W_ii_b = (const float*)d_in[4];
  const float* W_hi_w = (const float*)d_in[5];
  const float* W_hi_b = (const float*)d_in[6];
  const float* W_ci   = (const float*)d_in[7];
  const float* W_if_w = (const float*)d_in[8];
  const float* W_if_b = (const float*)d_in[9];
  const float* W_hf_w = (const float*)d_in[10];
  const float* W_hf_b = (const float*)d_in[11];
  const float* W_cf   = (const float*)d_in[12];
  const float* W_ig_w = (const float*)d_in[13];
  const float* W_ig_b = (const float*)d_in[14];
  const float* W_hg_w = (const float*)d_in[15];
  const float* W_hg_b = (const float*)d_in[16];
  const float* W_io_w = (const float*)d_in[17];
  const float* W_io_b = (const float*)d_in[18];
  const float* W_ho_w = (const float*)d_in[19];
  const float* W_ho_b = (const float*)d_in[20];
  const float* W_co   = (const float*)d_in[21];

  // ws: A bf16 [4096][2048] (16MB) | Bm bf16 [4096][2048] (16MB)
  unsigned short* Apack = (unsigned short*)d_ws;
  unsigned short* Bpack = Apack + (size_t)BD * KD;
  float* out = (float*)d_out;

  pack_AB<<<dim3(16384), dim3(256), 0, stream>>>(
      x, h, W_ii_w, W_if_w, W_ig_w, W_io_w, W_hi_w, W_hf_w, W_hg_w, W_ho_w,
      Apack, Bpack);
  gemm_lstm<<<dim3(256), dim3(512), 0, stream>>>(
      Apack, Bpack, c,
      W_ii_b, W_hi_b, W_if_b, W_hf_b, W_ig_b, W_hg_b, W_io_b, W_ho_b,
      W_ci, W_cf, W_co, out);
}